// Round 2
// baseline (2800.011 us; speedup 1.0000x reference)
//
#include <hip/hip_runtime.h>
#include <hip/hip_bf16.h>

// ---------- helpers ----------
__device__ __forceinline__ float b2f(unsigned short u) {
    return __uint_as_float(((unsigned)u) << 16);
}
__device__ __forceinline__ unsigned short f2b(float f) {
    __hip_bfloat16 h = __float2bfloat16(f);
    return *reinterpret_cast<unsigned short*>(&h);
}
__device__ __forceinline__ float gelu_exact(float v) {
    return 0.5f * v * (1.f + erff(v * 0.70710678118654752f));
}
__device__ __forceinline__ float sigm(float v) {
    return 1.f / (1.f + __expf(-v));
}

// ---------- dtype detection ----------
// Sample even-indexed ushorts of pe_w as bf16. If inputs are bf16, these are
// genuine N(0,0.05^2) weights: |v| < 1 always -> cnt==0. If inputs are f32,
// even ushorts are f32 mantissa bits -> random exponent -> ~half have |v|>=1.
// flag=1 means f32 inputs.
__global__ __launch_bounds__(256) void detect_kernel(
    const unsigned short* __restrict__ pe_w, int* __restrict__ flag)
{
    __shared__ int cnt;
    if (threadIdx.x == 0) cnt = 0;
    __syncthreads();
    float v = b2f(pe_w[threadIdx.x * 2]);
    int bad = (!(fabsf(v) < 1.0f)) ? 1 : 0;   // catches NaN/inf too
    if (bad) atomicAdd(&cnt, 1);
    __syncthreads();
    if (threadIdx.x == 0) *flag = (cnt >= 16) ? 1 : 0;
}

// ---------- canonicalize all inputs to bf16 ----------
struct ConvArgs {
    const void* p[22];
    int off[23];
};

__global__ __launch_bounds__(256) void convert_kernel(
    ConvArgs a, const int* __restrict__ flag,
    unsigned short* __restrict__ canon, int total)
{
    int g = blockIdx.x * 256 + threadIdx.x;
    if (g >= total) return;
    int s = 0;
    #pragma unroll
    for (int i = 1; i < 23; i++) s += (g >= a.off[i]) ? 1 : 0;
    int local = g - a.off[s];
    unsigned short r;
    if (*flag) r = f2b(((const float*)a.p[s])[local]);
    else       r = ((const unsigned short*)a.p[s])[local];
    canon[g] = r;
}

// ---------- positional encoding: out[r][d] = sin(feats(x_r) . w[:,d] + b[d]) ----------
__global__ __launch_bounds__(256) void encode_kernel(
    const unsigned short* __restrict__ pts,
    const unsigned short* __restrict__ w,   // [30][128] bf16
    const unsigned short* __restrict__ b,   // [128] bf16
    float* __restrict__ out)
{
    __shared__ __align__(16) float wsm[30 * 128];
    __shared__ float bs[128];
    int t = threadIdx.x;
    for (int i = t; i < 30 * 128; i += 256) wsm[i] = b2f(w[i]);
    if (t < 128) bs[t] = b2f(b[t]);
    __syncthreads();

    int r = blockIdx.x * 8 + (t >> 5);
    int j = t & 31;
    float x0 = b2f(pts[r * 2 + 0]);
    float x1 = b2f(pts[r * 2 + 1]);
    const float PI = 3.14159265358979323846f;
    float a0 = x0 - 1.5f, a1 = x1 - 1.5f, c0 = x0 - 4.5f, c1 = x1 - 4.5f;
    float f[30];
    f[0] = x0;        f[1] = x1;
    f[2] = x0 * x0;   f[3] = x1 * x1;
    f[4] = a0 * a0;   f[5] = a1 * a1;
    f[6] = c0 * c0;   f[7] = c1 * c1;
    f[8] = sigm(x0);  f[9] = sigm(x1);
    f[10] = sigm(a0); f[11] = sigm(a1);
    f[12] = sigm(c0); f[13] = sigm(c1);
    f[14] = a0;       f[15] = a1;
    f[16] = c0;       f[17] = c1;
    f[18] = __sinf(PI * x0);          f[19] = __sinf(PI * x1);
    f[20] = __cosf(PI * x0);          f[21] = __cosf(PI * x1);
    f[22] = __sinf(PI * 0.25f * x0);  f[23] = __sinf(PI * 0.25f * x1);
    f[24] = __cosf(PI * 0.25f * x0);  f[25] = __cosf(PI * 0.25f * x1);
    f[26] = __sinf(PI * 0.5f * x0);   f[27] = __sinf(PI * 0.5f * x1);
    f[28] = __cosf(PI * 0.5f * x0);   f[29] = __cosf(PI * 0.5f * x1);

    float s0 = bs[j * 4 + 0], s1 = bs[j * 4 + 1], s2 = bs[j * 4 + 2], s3 = bs[j * 4 + 3];
    #pragma unroll
    for (int ff = 0; ff < 30; ff++) {
        float4 wv = *(const float4*)&wsm[ff * 128 + j * 4];
        float fv = f[ff];
        s0 += fv * wv.x; s1 += fv * wv.y; s2 += fv * wv.z; s3 += fv * wv.w;
    }
    *(float4*)&out[(size_t)r * 128 + j * 4] =
        make_float4(__sinf(s0), __sinf(s1), __sinf(s2), __sinf(s3));
}

// ---------- zero scratch ----------
__global__ void zero_kernel(float* __restrict__ p, int n) {
    int i = blockIdx.x * 256 + threadIdx.x;
    if (i < n) p[i] = 0.f;
}

// ---------- boundary k/v heads: kh=(benc@Wk+bk)^2, vh=benc@Wv+bv ----------
__global__ __launch_bounds__(256) void khvh_kernel(
    const float* __restrict__ benc,
    const unsigned short* __restrict__ Wk, const unsigned short* __restrict__ bk,
    const unsigned short* __restrict__ Wv, const unsigned short* __restrict__ bv,
    float* __restrict__ kh, float* __restrict__ vh)
{
    int g = blockIdx.x * 256 + threadIdx.x;
    int lh = g >> 17;          // 4096*32 = 131072 per (l,h)
    int rem = g & 131071;
    int m = rem >> 5;
    int dd = rem & 31;
    const unsigned short* wk = Wk + lh * 4096 + dd;
    const unsigned short* wv = Wv + lh * 4096 + dd;
    const float* br = benc + (size_t)m * 128;
    float ka = 0.f, va = 0.f;
    #pragma unroll 8
    for (int c = 0; c < 128; c++) {
        float bb = br[c];
        ka += bb * b2f(wk[c * 32]);
        va += bb * b2f(wv[c * 32]);
    }
    ka += b2f(bk[lh * 32 + dd]); ka = ka * ka;
    va += b2f(bv[lh * 32 + dd]);
    kh[g] = ka; vh[g] = va;
}

// ---------- reduce over boundary points: kvsum[lh][d][e], ksum[lh][d] ----------
__global__ __launch_bounds__(1024) void kvred_kernel(
    const float* __restrict__ kh, const float* __restrict__ vh,
    float* __restrict__ kvsum, float* __restrict__ ksum)
{
    __shared__ float khs[1024];
    __shared__ float vhs[1024];
    int t = threadIdx.x;
    int lh = blockIdx.x >> 3;
    int part = blockIdx.x & 7;
    int dd = t >> 5, ee = t & 31;
    float kva = 0.f, ksa = 0.f;
    for (int ch = 0; ch < 16; ch++) {
        int base = lh * 131072 + (part * 16 + ch) * 1024;
        khs[t] = kh[base + t];
        vhs[t] = vh[base + t];
        __syncthreads();
        #pragma unroll
        for (int i = 0; i < 32; i++) {
            float kk = khs[i * 32 + dd];
            kva += kk * vhs[i * 32 + ee];
            ksa += kk;
        }
        __syncthreads();
    }
    atomicAdd(&kvsum[lh * 1024 + dd * 32 + ee], kva);
    if (ee == 0) atomicAdd(&ksum[lh * 32 + dd], ksa);
}

// ---------- 32x128 @ 128x128 register-tile matmul from LDS ----------
__device__ __forceinline__ void mm_tile(
    const float* __restrict__ A, const unsigned short* __restrict__ W,
    int r0l, int j4, float acc[4][4])
{
    #pragma unroll
    for (int i = 0; i < 4; i++)
        #pragma unroll
        for (int k = 0; k < 4; k++) acc[i][k] = 0.f;
    #pragma unroll 8
    for (int c4 = 0; c4 < 32; c4++) {
        float4 a0 = *(const float4*)&A[(r0l + 0) * 128 + c4 * 4];
        float4 a1 = *(const float4*)&A[(r0l + 1) * 128 + c4 * 4];
        float4 a2 = *(const float4*)&A[(r0l + 2) * 128 + c4 * 4];
        float4 a3 = *(const float4*)&A[(r0l + 3) * 128 + c4 * 4];
        ushort4 u0 = *(const ushort4*)&W[(c4 * 4 + 0) * 128 + j4];
        ushort4 u1 = *(const ushort4*)&W[(c4 * 4 + 1) * 128 + j4];
        ushort4 u2 = *(const ushort4*)&W[(c4 * 4 + 2) * 128 + j4];
        ushort4 u3 = *(const ushort4*)&W[(c4 * 4 + 3) * 128 + j4];
#define ACC4(ax0, ax1, ax2, ax3, uu) { \
        float w0 = b2f(uu.x), w1 = b2f(uu.y), w2 = b2f(uu.z), w3 = b2f(uu.w); \
        acc[0][0] += ax0 * w0; acc[0][1] += ax0 * w1; acc[0][2] += ax0 * w2; acc[0][3] += ax0 * w3; \
        acc[1][0] += ax1 * w0; acc[1][1] += ax1 * w1; acc[1][2] += ax1 * w2; acc[1][3] += ax1 * w3; \
        acc[2][0] += ax2 * w0; acc[2][1] += ax2 * w1; acc[2][2] += ax2 * w2; acc[2][3] += ax2 * w3; \
        acc[3][0] += ax3 * w0; acc[3][1] += ax3 * w1; acc[3][2] += ax3 * w2; acc[3][3] += ax3 * w3; }
        ACC4(a0.x, a1.x, a2.x, a3.x, u0);
        ACC4(a0.y, a1.y, a2.y, a3.y, u1);
        ACC4(a0.z, a1.z, a2.z, a3.z, u2);
        ACC4(a0.w, a1.w, a2.w, a3.w, u3);
#undef ACC4
    }
}

// ---------- fused transformer layer (in-place on h) ----------
__global__ __launch_bounds__(256) void layer_kernel(
    float* __restrict__ hbuf,
    const unsigned short* __restrict__ Wq, const unsigned short* __restrict__ bq,
    const unsigned short* __restrict__ Wo, const unsigned short* __restrict__ bo,
    const unsigned short* __restrict__ W1, const unsigned short* __restrict__ b1,
    const unsigned short* __restrict__ W2, const unsigned short* __restrict__ b2,
    const float* __restrict__ kvsum, const float* __restrict__ ksum, int l)
{
    __shared__ __align__(16) float hs[32 * 128];
    __shared__ __align__(16) float qs[32 * 128];
    __shared__ __align__(16) unsigned short wsm[128 * 128];
    int t = threadIdx.x;
    size_t row0 = (size_t)blockIdx.x * 32;
    float* hrow = hbuf + row0 * 128;

    {
        float4* hs4 = (float4*)hs;
        const float4* hg4 = (const float4*)hrow;
        #pragma unroll
        for (int i = 0; i < 4; i++) hs4[t + i * 256] = hg4[t + i * 256];
    }
    // stage Wq with head interleave: wsm[c*128 + (h*32+d)] = Wq[l][h][c][d]
    {
        const unsigned short* wqg = Wq + (size_t)l * 16384;
        ushort4* d4 = (ushort4*)wsm;
        #pragma unroll
        for (int ii = 0; ii < 16; ii++) {
            int i = t + ii * 256;
            int idx = i * 4; int c = idx >> 7; int j = idx & 127;
            int hh = j >> 5; int dd = j & 31;
            d4[i] = *(const ushort4*)(wqg + hh * 4096 + c * 32 + dd);
        }
    }
    __syncthreads();

    int j4 = (t & 31) * 4;
    int r0l = (t >> 5) * 4;
    float acc[4][4];

    // qh = (h @ Wq + bq)^2
    mm_tile(hs, wsm, r0l, j4, acc);
    {
        const unsigned short* bp = bq + l * 128 + j4;
        float b0 = b2f(bp[0]), b1v = b2f(bp[1]), b2v = b2f(bp[2]), b3v = b2f(bp[3]);
        #pragma unroll
        for (int i = 0; i < 4; i++) {
            float v0 = acc[i][0] + b0, v1 = acc[i][1] + b1v, v2 = acc[i][2] + b2v, v3 = acc[i][3] + b3v;
            *(float4*)&qs[(r0l + i) * 128 + j4] = make_float4(v0 * v0, v1 * v1, v2 * v2, v3 * v3);
        }
    }
    __syncthreads();

    // linear attention: at = (qh @ kvsum) / (qh . ksum + 1e-6)
    {
        int hh = j4 >> 5; int e0 = j4 & 31;
        const float* kvp = kvsum + (l * 4 + hh) * 1024;
        const float* ksp = ksum + (l * 4 + hh) * 32;
        float at[4][4]; float sden[4];
        #pragma unroll
        for (int i = 0; i < 4; i++) {
            sden[i] = 0.f;
            #pragma unroll
            for (int k = 0; k < 4; k++) at[i][k] = 0.f;
        }
        #pragma unroll 4
        for (int d = 0; d < 32; d++) {
            float4 kv = *(const float4*)&kvp[d * 32 + e0];
            float kd = ksp[d];
            #pragma unroll
            for (int i = 0; i < 4; i++) {
                float q = qs[(r0l + i) * 128 + hh * 32 + d];
                sden[i] += q * kd;
                at[i][0] += q * kv.x; at[i][1] += q * kv.y;
                at[i][2] += q * kv.z; at[i][3] += q * kv.w;
            }
        }
        __syncthreads();
        #pragma unroll
        for (int i = 0; i < 4; i++) {
            float z = 1.f / (sden[i] + 1e-6f);
            *(float4*)&qs[(r0l + i) * 128 + j4] =
                make_float4(at[i][0] * z, at[i][1] * z, at[i][2] * z, at[i][3] * z);
        }
    }
    {
        const ushort4* s4 = (const ushort4*)(Wo + (size_t)l * 16384);
        ushort4* d4 = (ushort4*)wsm;
        #pragma unroll
        for (int ii = 0; ii < 16; ii++) d4[t + ii * 256] = s4[t + ii * 256];
    }
    __syncthreads();

    // x = h + attn @ Wo + bo
    mm_tile(qs, wsm, r0l, j4, acc);
    {
        const unsigned short* bp = bo + l * 128 + j4;
        float b0 = b2f(bp[0]), b1v = b2f(bp[1]), b2v = b2f(bp[2]), b3v = b2f(bp[3]);
        #pragma unroll
        for (int i = 0; i < 4; i++) {
            float* hp = &hs[(r0l + i) * 128 + j4];
            hp[0] += acc[i][0] + b0; hp[1] += acc[i][1] + b1v;
            hp[2] += acc[i][2] + b2v; hp[3] += acc[i][3] + b3v;
        }
    }
    __syncthreads();
    {
        const ushort4* s4 = (const ushort4*)(W1 + (size_t)l * 16384);
        ushort4* d4 = (ushort4*)wsm;
        #pragma unroll
        for (int ii = 0; ii < 16; ii++) d4[t + ii * 256] = s4[t + ii * 256];
    }
    __syncthreads();

    // t = gelu(x @ W1 + b1) -> qs
    mm_tile(hs, wsm, r0l, j4, acc);
    {
        const unsigned short* bp = b1 + l * 128 + j4;
        float b0 = b2f(bp[0]), b1v = b2f(bp[1]), b2v = b2f(bp[2]), b3v = b2f(bp[3]);
        #pragma unroll
        for (int i = 0; i < 4; i++) {
            *(float4*)&qs[(r0l + i) * 128 + j4] = make_float4(
                gelu_exact(acc[i][0] + b0), gelu_exact(acc[i][1] + b1v),
                gelu_exact(acc[i][2] + b2v), gelu_exact(acc[i][3] + b3v));
        }
    }
    __syncthreads();
    {
        const ushort4* s4 = (const ushort4*)(W2 + (size_t)l * 16384);
        ushort4* d4 = (ushort4*)wsm;
        #pragma unroll
        for (int ii = 0; ii < 16; ii++) d4[t + ii * 256] = s4[t + ii * 256];
    }
    __syncthreads();

    // h_new = x + t @ W2 + b2 -> global
    mm_tile(qs, wsm, r0l, j4, acc);
    {
        const unsigned short* bp = b2 + l * 128 + j4;
        float b0 = b2f(bp[0]), b1v = b2f(bp[1]), b2v = b2f(bp[2]), b3v = b2f(bp[3]);
        #pragma unroll
        for (int i = 0; i < 4; i++) {
            const float* hp = &hs[(r0l + i) * 128 + j4];
            *(float4*)&hrow[(r0l + i) * 128 + j4] = make_float4(
                hp[0] + acc[i][0] + b0, hp[1] + acc[i][1] + b1v,
                hp[2] + acc[i][2] + b2v, hp[3] + acc[i][3] + b3v);
        }
    }
}

// ---------- final projector: out = gelu(h@pw1+pb1)@pw2 + pb2 ----------
__global__ __launch_bounds__(256) void final_kernel(
    const float* __restrict__ hbuf,
    const unsigned short* __restrict__ pw1, const unsigned short* __restrict__ pb1,
    const unsigned short* __restrict__ pw2, const unsigned short* __restrict__ pb2,
    void* __restrict__ outv, const int* __restrict__ flag)
{
    __shared__ __align__(16) float hsf[32 * 128];   // 16K
    __shared__ __align__(16) float w1s[128 * 64];   // 32K
    __shared__ __align__(16) float tsf[32 * 64];    // 8K
    __shared__ float w2s[192];
    __shared__ float pbs[68];
    int t = threadIdx.x;
    size_t row0 = (size_t)blockIdx.x * 32;
    {
        const float4* hg4 = (const float4*)(hbuf + row0 * 128);
        float4* hs4 = (float4*)hsf;
        #pragma unroll
        for (int i = 0; i < 4; i++) hs4[t + i * 256] = hg4[t + i * 256];
    }
    for (int i = t; i < 8192; i += 256) w1s[i] = b2f(pw1[i]);
    if (t < 192) w2s[t] = b2f(pw2[t]);
    if (t < 64) pbs[t] = b2f(pb1[t]);
    if (t >= 64 && t < 67) pbs[t] = b2f(pb2[t - 64]);
    __syncthreads();

    int j4 = (t & 15) * 4;
    int r0l = (t >> 4) * 2;
    float acc[2][4];
    #pragma unroll
    for (int i = 0; i < 2; i++)
        #pragma unroll
        for (int k = 0; k < 4; k++) acc[i][k] = 0.f;
    #pragma unroll 4
    for (int c4 = 0; c4 < 32; c4++) {
        float4 a0 = *(const float4*)&hsf[(r0l + 0) * 128 + c4 * 4];
        float4 a1 = *(const float4*)&hsf[(r0l + 1) * 128 + c4 * 4];
        float a0v[4] = {a0.x, a0.y, a0.z, a0.w};
        float a1v[4] = {a1.x, a1.y, a1.z, a1.w};
        #pragma unroll
        for (int ii = 0; ii < 4; ii++) {
            float4 wv = *(const float4*)&w1s[(c4 * 4 + ii) * 64 + j4];
            acc[0][0] += a0v[ii] * wv.x; acc[0][1] += a0v[ii] * wv.y;
            acc[0][2] += a0v[ii] * wv.z; acc[0][3] += a0v[ii] * wv.w;
            acc[1][0] += a1v[ii] * wv.x; acc[1][1] += a1v[ii] * wv.y;
            acc[1][2] += a1v[ii] * wv.z; acc[1][3] += a1v[ii] * wv.w;
        }
    }
    #pragma unroll
    for (int i = 0; i < 2; i++)
        #pragma unroll
        for (int k = 0; k < 4; k++)
            tsf[(r0l + i) * 64 + j4 + k] = gelu_exact(acc[i][k] + pbs[j4 + k]);
    __syncthreads();

    int r = t >> 2, k = t & 3;
    if (r < 32 && k < 3) {
        float s = pbs[64 + k];
        #pragma unroll 8
        for (int c = 0; c < 64; c++) s += tsf[r * 64 + c] * w2s[c * 3 + k];
        if (*flag) ((float*)outv)[(row0 + r) * 3 + k] = s;
        else       ((unsigned short*)outv)[(row0 + r) * 3 + k] = f2b(s);
    }
}

// ---------- launch ----------
extern "C" void kernel_launch(void* const* d_in, const int* in_sizes, int n_in,
                              void* d_out, int out_size, void* d_ws, size_t ws_size,
                              hipStream_t stream) {
    const int N = in_sizes[0] / 2;   // 262144
    const int M = in_sizes[1] / 2;   // 4096

    // canonical-input offsets
    ConvArgs ca;
    int total = 0;
    for (int i = 0; i < 22; i++) { ca.p[i] = d_in[i]; ca.off[i] = total; total += in_sizes[i]; }
    ca.off[22] = total;

    float* ws = (float*)d_ws;
    int* flag = (int*)ws;                                  // ws[0]
    unsigned short* canon = (unsigned short*)(ws + 16);    // 64B in
    size_t canonF = ((size_t)(total + 1) / 2 + 15) & ~(size_t)15;
    float* h_buf = ws + 16 + canonF;                       // N*128
    float* b_enc = h_buf + (size_t)N * 128;                // M*128
    float* khb   = b_enc + (size_t)M * 128;                // 12*M*32
    float* vhb   = khb + (size_t)12 * M * 32;              // 12*M*32
    float* kvs   = vhb + (size_t)12 * M * 32;              // 12288
    float* kss   = kvs + 12288;                            // 384

    const unsigned short* c_qpts = canon + ca.off[0];
    const unsigned short* c_bpts = canon + ca.off[1];
    const unsigned short* c_pew  = canon + ca.off[2];
    const unsigned short* c_peb  = canon + ca.off[3];
    const unsigned short* c_bpew = canon + ca.off[4];
    const unsigned short* c_bpeb = canon + ca.off[5];
    const unsigned short* c_Wq   = canon + ca.off[6];
    const unsigned short* c_bq   = canon + ca.off[7];
    const unsigned short* c_Wk   = canon + ca.off[8];
    const unsigned short* c_bk   = canon + ca.off[9];
    const unsigned short* c_Wv   = canon + ca.off[10];
    const unsigned short* c_bv   = canon + ca.off[11];
    const unsigned short* c_Wo   = canon + ca.off[12];
    const unsigned short* c_bo   = canon + ca.off[13];
    const unsigned short* c_W1   = canon + ca.off[14];
    const unsigned short* c_b1   = canon + ca.off[15];
    const unsigned short* c_W2   = canon + ca.off[16];
    const unsigned short* c_b2   = canon + ca.off[17];
    const unsigned short* c_pw1  = canon + ca.off[18];
    const unsigned short* c_pb1  = canon + ca.off[19];
    const unsigned short* c_pw2  = canon + ca.off[20];
    const unsigned short* c_pb2  = canon + ca.off[21];

    detect_kernel<<<1, 256, 0, stream>>>((const unsigned short*)d_in[2], flag);
    convert_kernel<<<(total + 255) / 256, 256, 0, stream>>>(ca, flag, canon, total);

    encode_kernel<<<N / 8, 256, 0, stream>>>(c_qpts, c_pew, c_peb, h_buf);
    encode_kernel<<<M / 8, 256, 0, stream>>>(c_bpts, c_bpew, c_bpeb, b_enc);
    zero_kernel<<<50, 256, 0, stream>>>(kvs, 12288 + 384);
    khvh_kernel<<<(12 * M * 32) / 256, 256, 0, stream>>>(b_enc, c_Wk, c_bk, c_Wv, c_bv, khb, vhb);
    kvred_kernel<<<96, 1024, 0, stream>>>(khb, vhb, kvs, kss);
    for (int l = 0; l < 3; l++) {
        layer_kernel<<<N / 32, 256, 0, stream>>>(h_buf, c_Wq, c_bq, c_Wo, c_bo,
                                                 c_W1, c_b1, c_W2, c_b2, kvs, kss, l);
    }
    final_kernel<<<N / 32, 256, 0, stream>>>(h_buf, c_pw1, c_pb1, c_pw2, c_pb2, d_out, flag);
}

// Round 4
// 877.602 us; speedup vs baseline: 3.1905x; 3.1905x over previous
//
#include <hip/hip_runtime.h>
#include <hip/hip_bf16.h>

// ---------- helpers ----------
__device__ __forceinline__ float b2f(unsigned short u) {
    return __uint_as_float(((unsigned)u) << 16);
}
__device__ __forceinline__ unsigned short f2b(float f) {
    __hip_bfloat16 h = __float2bfloat16(f);
    return *reinterpret_cast<unsigned short*>(&h);
}
__device__ __forceinline__ float gelu_exact(float v) {
    return 0.5f * v * (1.f + erff(v * 0.70710678118654752f));
}
__device__ __forceinline__ float sigm(float v) {
    return 1.f / (1.f + __expf(-v));
}

typedef __attribute__((ext_vector_type(8))) short s8v;   // 8 bf16 (4 VGPRs)
typedef __attribute__((ext_vector_type(4))) float f4v;   // 4 fp32 acc

#define MFMA_BF16 __builtin_amdgcn_mfma_f32_16x16x32_bf16

// ---------- dtype detection (f32 vs bf16 inputs) ----------
__global__ __launch_bounds__(256) void detect_kernel(
    const unsigned short* __restrict__ pe_w, int* __restrict__ flag)
{
    __shared__ int cnt;
    if (threadIdx.x == 0) cnt = 0;
    __syncthreads();
    float v = b2f(pe_w[threadIdx.x * 2]);
    int bad = (!(fabsf(v) < 1.0f)) ? 1 : 0;
    if (bad) atomicAdd(&cnt, 1);
    __syncthreads();
    if (threadIdx.x == 0) *flag = (cnt >= 16) ? 1 : 0;
}

// ---------- canonicalize all inputs to bf16 ----------
struct ConvArgs {
    const void* p[22];
    int off[23];
};

__global__ __launch_bounds__(256) void convert_kernel(
    ConvArgs a, const int* __restrict__ flag,
    unsigned short* __restrict__ canon, int total)
{
    int g = blockIdx.x * 256 + threadIdx.x;
    if (g >= total) return;
    int s = 0;
    #pragma unroll
    for (int i = 1; i < 23; i++) s += (g >= a.off[i]) ? 1 : 0;
    int local = g - a.off[s];
    unsigned short r;
    if (*flag) r = f2b(((const float*)a.p[s])[local]);
    else       r = ((const unsigned short*)a.p[s])[local];
    canon[g] = r;
}

// ---------- boundary positional encoding (M rows, fp32 out) ----------
__global__ __launch_bounds__(256) void encode_kernel(
    const unsigned short* __restrict__ pts,
    const unsigned short* __restrict__ w,
    const unsigned short* __restrict__ b,
    float* __restrict__ out)
{
    __shared__ __align__(16) float wsm[30 * 128];
    __shared__ float bs[128];
    int t = threadIdx.x;
    for (int i = t; i < 30 * 128; i += 256) wsm[i] = b2f(w[i]);
    if (t < 128) bs[t] = b2f(b[t]);
    __syncthreads();

    int r = blockIdx.x * 8 + (t >> 5);
    int j = t & 31;
    float x0 = b2f(pts[r * 2 + 0]);
    float x1 = b2f(pts[r * 2 + 1]);
    const float PI = 3.14159265358979323846f;
    float a0 = x0 - 1.5f, a1 = x1 - 1.5f, c0 = x0 - 4.5f, c1 = x1 - 4.5f;
    float f[30];
    f[0] = x0;        f[1] = x1;
    f[2] = x0 * x0;   f[3] = x1 * x1;
    f[4] = a0 * a0;   f[5] = a1 * a1;
    f[6] = c0 * c0;   f[7] = c1 * c1;
    f[8] = sigm(x0);  f[9] = sigm(x1);
    f[10] = sigm(a0); f[11] = sigm(a1);
    f[12] = sigm(c0); f[13] = sigm(c1);
    f[14] = a0;       f[15] = a1;
    f[16] = c0;       f[17] = c1;
    f[18] = __sinf(PI * x0);          f[19] = __sinf(PI * x1);
    f[20] = __cosf(PI * x0);          f[21] = __cosf(PI * x1);
    f[22] = __sinf(PI * 0.25f * x0);  f[23] = __sinf(PI * 0.25f * x1);
    f[24] = __cosf(PI * 0.25f * x0);  f[25] = __cosf(PI * 0.25f * x1);
    f[26] = __sinf(PI * 0.5f * x0);   f[27] = __sinf(PI * 0.5f * x1);
    f[28] = __cosf(PI * 0.5f * x0);   f[29] = __cosf(PI * 0.5f * x1);

    float s0 = bs[j * 4 + 0], s1 = bs[j * 4 + 1], s2 = bs[j * 4 + 2], s3 = bs[j * 4 + 3];
    #pragma unroll
    for (int ff = 0; ff < 30; ff++) {
        float4 wv = *(const float4*)&wsm[ff * 128 + j * 4];
        float fv = f[ff];
        s0 += fv * wv.x; s1 += fv * wv.y; s2 += fv * wv.z; s3 += fv * wv.w;
    }
    *(float4*)&out[(size_t)r * 128 + j * 4] =
        make_float4(__sinf(s0), __sinf(s1), __sinf(s2), __sinf(s3));
}

// ---------- zero scratch ----------
__global__ void zero_kernel(float* __restrict__ p, int n) {
    int i = blockIdx.x * 256 + threadIdx.x;
    if (i < n) p[i] = 0.f;
}

// ---------- boundary k/v heads ----------
__global__ __launch_bounds__(256) void khvh_kernel(
    const float* __restrict__ benc,
    const unsigned short* __restrict__ Wk, const unsigned short* __restrict__ bk,
    const unsigned short* __restrict__ Wv, const unsigned short* __restrict__ bv,
    float* __restrict__ kh, float* __restrict__ vh)
{
    int g = blockIdx.x * 256 + threadIdx.x;
    int lh = g >> 17;
    int rem = g & 131071;
    int m = rem >> 5;
    int dd = rem & 31;
    const unsigned short* wk = Wk + lh * 4096 + dd;
    const unsigned short* wv = Wv + lh * 4096 + dd;
    const float* br = benc + (size_t)m * 128;
    float ka = 0.f, va = 0.f;
    #pragma unroll 8
    for (int c = 0; c < 128; c++) {
        float bb = br[c];
        ka += bb * b2f(wk[c * 32]);
        va += bb * b2f(wv[c * 32]);
    }
    ka += b2f(bk[lh * 32 + dd]); ka = ka * ka;
    va += b2f(bv[lh * 32 + dd]);
    kh[g] = ka; vh[g] = va;
}

// ---------- reduce over boundary points: kvsum[lh][d][e], ksum[lh][d] ----------
__global__ __launch_bounds__(1024) void kvred_kernel(
    const float* __restrict__ kh, const float* __restrict__ vh,
    float* __restrict__ kvsum, float* __restrict__ ksum)
{
    __shared__ float khs[1024];
    __shared__ float vhs[1024];
    int t = threadIdx.x;
    int lh = blockIdx.x >> 3;
    int part = blockIdx.x & 7;
    int dd = t >> 5, ee = t & 31;
    float kva = 0.f, ksa = 0.f;
    for (int ch = 0; ch < 16; ch++) {
        int base = lh * 131072 + (part * 16 + ch) * 1024;
        khs[t] = kh[base + t];
        vhs[t] = vh[base + t];
        __syncthreads();
        #pragma unroll
        for (int i = 0; i < 32; i++) {
            float kk = khs[i * 32 + dd];
            kva += kk * vhs[i * 32 + ee];
            ksa += kk;
        }
        __syncthreads();
    }
    atomicAdd(&kvsum[lh * 1024 + dd * 32 + ee], kva);
    if (ee == 0) atomicAdd(&ksum[lh * 32 + dd], ksa);
}

// ---------- prep: transpose weights into B-fragment layout [n][k] ----------
__global__ __launch_bounds__(256) void prep_trans_kernel(
    const unsigned short* __restrict__ Wq, const unsigned short* __restrict__ W1,
    const unsigned short* __restrict__ W2, const unsigned short* __restrict__ pw1,
    unsigned short* __restrict__ wqT, unsigned short* __restrict__ w1T,
    unsigned short* __restrict__ w2T, unsigned short* __restrict__ pw1T)
{
    int g = blockIdx.x * 256 + threadIdx.x;
    if (g < 49152) {
        int l = g >> 14, r = g & 16383, n = r >> 7, k = r & 127;
        // head-interleaved: col n = h*32+d
        wqT[g] = Wq[((l * 4 + (n >> 5)) * 128 + k) * 32 + (n & 31)];
    } else if (g < 98304) {
        int q = g - 49152; int l = q >> 14, r = q & 16383, n = r >> 7, k = r & 127;
        w1T[q] = W1[(l * 128 + k) * 128 + n];
    } else if (g < 147456) {
        int q = g - 98304; int l = q >> 14, r = q & 16383, n = r >> 7, k = r & 127;
        w2T[q] = W2[(l * 128 + k) * 128 + n];
    } else if (g < 155648) {
        int q = g - 147456; int n = q >> 7, k = q & 127;
        pw1T[q] = pw1[k * 64 + n];
    }
}

// ---------- prep: Wa = KV_blockdiag @ Wo (transposed, bf16) + Ks ----------
__global__ __launch_bounds__(256) void prep_wa_kernel(
    const float* __restrict__ kvs, const float* __restrict__ kss,
    const unsigned short* __restrict__ Wo,
    unsigned short* __restrict__ waT, unsigned short* __restrict__ ksT)
{
    int g = blockIdx.x * 256 + threadIdx.x;
    if (g < 49152) {
        int l = g >> 14, r = g & 16383, n = r >> 7, k = r & 127;
        int hk = k >> 5, dk = k & 31;
        const float* kvp = kvs + (l * 4 + hk) * 1024 + dk * 32;
        const unsigned short* wop = Wo + (size_t)(l * 128 + hk * 32) * 128 + n;
        float s = 0.f;
        #pragma unroll 8
        for (int j = 0; j < 32; j++) s += kvp[j] * b2f(wop[j * 128]);
        waT[g] = f2b(s);
    } else if (g < 55296) {
        int q = g - 49152; int l = q >> 11, r = q & 2047, n = r >> 7, k = r & 127;
        unsigned short v = 0;
        if (n < 4 && (k >> 5) == n) v = f2b(kss[(l * 4 + n) * 32 + (k & 31)]);
        ksT[q] = v;
    }
}

// ---------- the fused mega kernel: encode + 3 layers + projector ----------
// 64 rows/block, 4 waves; wave w owns rows w*16..w*16+15 (all 128 cols).
// MFMA 16x16x32 bf16. A-frag: A[m=lane&15][k=quad*8+j]; B-frag: B[k][n=lane&15];
// C/D: row=quad*4+reg, col=lane&15 (m89-verified).
// h residual carried fp32 in registers (C-layout) through all 3 layers.
#define LDA 136   // LDS row stride in ushorts (272B = 17*16B: aligned, conflict-free)

__global__ __launch_bounds__(256) void mega_kernel(
    const unsigned short* __restrict__ qpts,
    const unsigned short* __restrict__ pe_w,
    const unsigned short* __restrict__ pe_b,
    const unsigned short* __restrict__ wqT,
    const unsigned short* __restrict__ waT,
    const unsigned short* __restrict__ ksT,
    const unsigned short* __restrict__ w1T,
    const unsigned short* __restrict__ w2T,
    const unsigned short* __restrict__ bq,
    const unsigned short* __restrict__ bo,
    const unsigned short* __restrict__ b1,
    const unsigned short* __restrict__ b2,
    const unsigned short* __restrict__ pw1T,
    const unsigned short* __restrict__ pb1,
    const unsigned short* __restrict__ pw2,
    const unsigned short* __restrict__ pb2,
    void* __restrict__ outv, const int* __restrict__ flag)
{
    __shared__ __align__(16) unsigned short sA[64 * LDA];     // 17408 B
    __shared__ __align__(16) unsigned short sB[64 * LDA];     // 17408 B
    __shared__ __align__(16) unsigned short wbuf[128 * LDA];  // 34816 B
    __shared__ __align__(16) unsigned short sKs[16 * LDA];    // 4352 B
    __shared__ float dens[64 * 4];
    __shared__ float bqs[128], bos[128], b1s[128], b2s[128];
    __shared__ float w2s[192];
    __shared__ float pb2s[4];

    int t = threadIdx.x;
    int wv = t >> 6, ln = t & 63, qd = ln >> 4, l16 = ln & 15;
    int row0 = blockIdx.x * 64;
    int mrow = wv * 16 + l16;       // A-fragment row for this lane
    int crow = wv * 16 + qd * 4;    // C-fragment base row (+i)

    float hres[4][8];               // fp32 residual, C-layout: [i][tc]

    // ===== encode: h = sin(feats(x) @ pe_w + pe_b) for own 64 rows =====
    {
        float* pws = (float*)wbuf;      // [30][128] fp32
        float* pbsl = (float*)sKs;      // [128]
        for (int i = t; i < 3840; i += 256) pws[i] = b2f(pe_w[i]);
        if (t < 128) pbsl[t] = b2f(pe_b[t]);
        __syncthreads();
        const float PI = 3.14159265358979323846f;
        for (int i = 0; i < 4; i++) {
            int r = row0 + crow + i;
            float x0 = b2f(qpts[r * 2 + 0]);
            float x1 = b2f(qpts[r * 2 + 1]);
            float a0 = x0 - 1.5f, a1 = x1 - 1.5f, c0 = x0 - 4.5f, c1 = x1 - 4.5f;
            float f[30];
            f[0] = x0;        f[1] = x1;
            f[2] = x0 * x0;   f[3] = x1 * x1;
            f[4] = a0 * a0;   f[5] = a1 * a1;
            f[6] = c0 * c0;   f[7] = c1 * c1;
            f[8] = sigm(x0);  f[9] = sigm(x1);
            f[10] = sigm(a0); f[11] = sigm(a1);
            f[12] = sigm(c0); f[13] = sigm(c1);
            f[14] = a0;       f[15] = a1;
            f[16] = c0;       f[17] = c1;
            f[18] = __sinf(PI * x0);          f[19] = __sinf(PI * x1);
            f[20] = __cosf(PI * x0);          f[21] = __cosf(PI * x1);
            f[22] = __sinf(PI * 0.25f * x0);  f[23] = __sinf(PI * 0.25f * x1);
            f[24] = __cosf(PI * 0.25f * x0);  f[25] = __cosf(PI * 0.25f * x1);
            f[26] = __sinf(PI * 0.5f * x0);   f[27] = __sinf(PI * 0.5f * x1);
            f[28] = __cosf(PI * 0.5f * x0);   f[29] = __cosf(PI * 0.5f * x1);
            for (int tc = 0; tc < 8; tc++) {
                int c = tc * 16 + l16;
                float s = pbsl[c];
                #pragma unroll
                for (int ff = 0; ff < 30; ff++) s += f[ff] * pws[ff * 128 + c];
                float h = __sinf(s);
                hres[i][tc] = h;
                sA[(crow + i) * LDA + c] = f2b(h);
            }
        }
    }
    __syncthreads();

    // ===== 3 transformer layers =====
    for (int l = 0; l < 3; l++) {
        // ---- stage WqT + KsT + biases ----
        {
            const int4* src = (const int4*)(wqT + l * 16384);
            #pragma unroll
            for (int i = 0; i < 8; i++) {
                int idx = t + i * 256;
                *(int4*)&wbuf[(idx >> 4) * LDA + (idx & 15) * 8] = src[idx];
            }
            // sKs: 16 rows x 128 cols = 256 int4; one per thread.
            // source [n][k] linear: int4 t -> n = t>>4, k-offset = (t&15)*8
            *(int4*)&sKs[(t >> 4) * LDA + (t & 15) * 8] =
                ((const int4*)(ksT + l * 2048))[t];
            if (t < 128) {
                bqs[t] = b2f(bq[l * 128 + t]);
                bos[t] = b2f(bo[l * 128 + t]);
                b1s[t] = b2f(b1[l * 128 + t]);
                b2s[t] = b2f(b2[l * 128 + t]);
            }
        }
        __syncthreads();

        // ---- mm1: qh = (h @ Wq + bq)^2 -> sB (bf16) ----
        s8v af[4];
        #pragma unroll
        for (int ks = 0; ks < 4; ks++)
            af[ks] = *(const s8v*)&sA[mrow * LDA + ks * 32 + qd * 8];
        #pragma unroll
        for (int tc = 0; tc < 8; tc++) {
            f4v acc = {0.f, 0.f, 0.f, 0.f};
            #pragma unroll
            for (int ks = 0; ks < 4; ks++) {
                s8v bf = *(const s8v*)&wbuf[(tc * 16 + l16) * LDA + ks * 32 + qd * 8];
                acc = MFMA_BF16(af[ks], bf, acc, 0, 0, 0);
            }
            int c = tc * 16 + l16;
            float bb = bqs[c];
            #pragma unroll
            for (int i = 0; i < 4; i++) {
                float v = acc[i] + bb;
                sB[(crow + i) * LDA + c] = f2b(v * v);
            }
        }

        // ---- den MFMA: dens[r][h] = qh_r . ksum_h (unscaled qh) ----
        // same-wave ds_write->ds_read: per-wave LDS ops are in program order
        s8v qf[4];
        #pragma unroll
        for (int ks = 0; ks < 4; ks++)
            qf[ks] = *(const s8v*)&sB[mrow * LDA + ks * 32 + qd * 8];
        {
            f4v dacc = {0.f, 0.f, 0.f, 0.f};
            #pragma unroll
            for (int ks = 0; ks < 4; ks++) {
                s8v bf = *(const s8v*)&sKs[l16 * LDA + ks * 32 + qd * 8];
                dacc = MFMA_BF16(qf[ks], bf, dacc, 0, 0, 0);
            }
            if (l16 < 4) {
                #pragma unroll
                for (int i = 0; i < 4; i++) dens[(crow + i) * 4 + l16] = dacc[i];
            }
        }
        __syncthreads();

        // ---- stage WaT ----
        {
            const int4* src = (const int4*)(waT + l * 16384);
            #pragma unroll
            for (int i = 0; i < 8; i++) {
                int idx = t + i * 256;
                *(int4*)&wbuf[(idx >> 4) * LDA + (idx & 15) * 8] = src[idx];
            }
        }
        __syncthreads();

        // ---- scale qh frags by z = 1/(den+1e-6); head of frag ks == ks ----
        #pragma unroll
        for (int ks = 0; ks < 4; ks++) {
            float z = 1.f / (dens[mrow * 4 + ks] + 1e-6f);
            #pragma unroll
            for (int j = 0; j < 8; j++) {
                qf[ks][j] = (short)f2b(b2f((unsigned short)qf[ks][j]) * z);
            }
        }

        // ---- mm2: x = h + (z*qh) @ Wa + bo -> hres (fp32), sA (bf16) ----
        #pragma unroll
        for (int tc = 0; tc < 8; tc++) {
            f4v acc = {0.f, 0.f, 0.f, 0.f};
            #pragma unroll
            for (int ks = 0; ks < 4; ks++) {
                s8v bf = *(const s8v*)&wbuf[(tc * 16 + l16) * LDA + ks * 32 + qd * 8];
                acc = MFMA_BF16(qf[ks], bf, acc, 0, 0, 0);
            }
            int c = tc * 16 + l16;
            float bb = bos[c];
            #pragma unroll
            for (int i = 0; i < 4; i++) {
                float x = hres[i][tc] + acc[i] + bb;
                hres[i][tc] = x;
                sA[(crow + i) * LDA + c] = f2b(x);
            }
        }
        __syncthreads();

        // ---- stage W1T ----
        {
            const int4* src = (const int4*)(w1T + l * 16384);
            #pragma unroll
            for (int i = 0; i < 8; i++) {
                int idx = t + i * 256;
                *(int4*)&wbuf[(idx >> 4) * LDA + (idx & 15) * 8] = src[idx];
            }
        }
        __syncthreads();

        // ---- mm3: t = gelu(x @ W1 + b1) -> sB ----
        #pragma unroll
        for (int ks = 0; ks < 4; ks++)
            af[ks] = *(const s8v*)&sA[mrow * LDA + ks * 32 + qd * 8];
        #pragma unroll
        for (int tc = 0; tc < 8; tc++) {
            f4v acc = {0.f, 0.f, 0.f, 0.f};
            #pragma unroll
            for (int ks = 0; ks < 4; ks++) {
                s8v bf = *(const s8v*)&wbuf[(tc * 16 + l16) * LDA + ks * 32 + qd * 8];
                acc = MFMA_BF16(af[ks], bf, acc, 0, 0, 0);
            }
            int c = tc * 16 + l16;
            float bb = b1s[c];
            #pragma unroll
            for (int i = 0; i < 4; i++)
                sB[(crow + i) * LDA + c] = f2b(gelu_exact(acc[i] + bb));
        }
        __syncthreads();

        // ---- stage W2T ----
        {
            const int4* src = (const int4*)(w2T + l * 16384);
            #pragma unroll
            for (int i = 0; i < 8; i++) {
                int idx = t + i * 256;
                *(int4*)&wbuf[(idx >> 4) * LDA + (idx & 15) * 8] = src[idx];
            }
        }
        __syncthreads();

        // ---- mm4: h_new = x + t @ W2 + b2 -> hres, sA ----
        #pragma unroll
        for (int ks = 0; ks < 4; ks++)
            af[ks] = *(const s8v*)&sB[mrow * LDA + ks * 32 + qd * 8];
        #pragma unroll
        for (int tc = 0; tc < 8; tc++) {
            f4v acc = {0.f, 0.f, 0.f, 0.f};
            #pragma unroll
            for (int ks = 0; ks < 4; ks++) {
                s8v bf = *(const s8v*)&wbuf[(tc * 16 + l16) * LDA + ks * 32 + qd * 8];
                acc = MFMA_BF16(af[ks], bf, acc, 0, 0, 0);
            }
            int c = tc * 16 + l16;
            float bb = b2s[c];
            #pragma unroll
            for (int i = 0; i < 4; i++) {
                float hn = hres[i][tc] + acc[i] + bb;
                hres[i][tc] = hn;
                sA[(crow + i) * LDA + c] = f2b(hn);
            }
        }
        __syncthreads();
    }

    // ===== final projector: out = gelu(h @ pw1 + pb1) @ pw2 + pb2 =====
    {
        #pragma unroll
        for (int i = 0; i < 4; i++) {
            int idx = t + i * 256;
            *(int4*)&wbuf[(idx >> 4) * LDA + (idx & 15) * 8] = ((const int4*)pw1T)[idx];
        }
        if (t < 64)  bqs[t] = b2f(pb1[t]);       // reuse bqs for pb1
        if (t < 192) w2s[t] = b2f(pw2[t]);
        if (t < 3)   pb2s[t] = b2f(pb2[t]);
    }
    __syncthreads();

    {
        s8v af[4];
        #pragma unroll
        for (int ks = 0; ks < 4; ks++)
            af[ks] = *(const s8v*)&sA[mrow * LDA + ks * 32 + qd * 8];
        float* sBf = (float*)sB;   // [64][68] fp32 (same bytes, stride 68 f32 = 272B)
        #pragma unroll
        for (int tc = 0; tc < 4; tc++) {
            f4v acc = {0.f, 0.f, 0.f, 0.f};
            #pragma unroll
            for (int ks = 0; ks < 4; ks++) {
                s8v bf = *(const s8v*)&wbuf[(tc * 16 + l16) * LDA + ks * 32 + qd * 8];
                acc = MFMA_BF16(af[ks], bf, acc, 0, 0, 0);
            }
            int c = tc * 16 + l16;
            float bb = bqs[c];
            #pragma unroll
            for (int i = 0; i < 4; i++)
                sBf[(crow + i) * 68 + c] = gelu_exact(acc[i] + bb);
        }
    }
    __syncthreads();

    if (t < 192) {
        int r = t / 3, c = t - r * 3;
        const float* sBf = (const float*)sB;
        float s = pb2s[c];
        #pragma unroll 8
        for (int j = 0; j < 64; j++) s += sBf[r * 68 + j] * w2s[j * 3 + c];
        size_t o = (size_t)(row0 + r) * 3 + c;
        if (*flag) ((float*)outv)[o] = s;
        else       ((unsigned short*)outv)[o] = f2b(s);
    }
}

// ---------- launch ----------
extern "C" void kernel_launch(void* const* d_in, const int* in_sizes, int n_in,
                              void* d_out, int out_size, void* d_ws, size_t ws_size,
                              hipStream_t stream) {
    const int N = in_sizes[0] / 2;   // 262144
    const int M = in_sizes[1] / 2;   // 4096

    ConvArgs ca;
    int total = 0;
    for (int i = 0; i < 22; i++) { ca.p[i] = d_in[i]; ca.off[i] = total; total += in_sizes[i]; }
    ca.off[22] = total;

    float* ws = (float*)d_ws;
    int* flag = (int*)ws;
    unsigned short* canon = (unsigned short*)(ws + 16);
    size_t canonF = ((size_t)(total + 1) / 2 + 15) & ~(size_t)15;
    float* b_enc = ws + 16 + canonF;                       // M*128
    float* khb   = b_enc + (size_t)M * 128;                // 12*M*32
    float* vhb   = khb + (size_t)12 * M * 32;              // 12*M*32
    float* kvs   = vhb + (size_t)12 * M * 32;              // 12288
    float* kss   = kvs + 12288;                            // 384
    unsigned short* wqT  = (unsigned short*)(kss + 384);   // 3*16384
    unsigned short* waT  = wqT + 49152;
    unsigned short* w1T  = waT + 49152;
    unsigned short* w2T  = w1T + 49152;
    unsigned short* ksT  = w2T + 49152;                    // 3*2048
    unsigned short* pw1T = ksT + 6144;                     // 8192

    const unsigned short* c_qpts = canon + ca.off[0];
    const unsigned short* c_bpts = canon + ca.off[1];
    const unsigned short* c_pew  = canon + ca.off[2];
    const unsigned short* c_peb  = canon + ca.off[3];
    const unsigned short* c_bpew = canon + ca.off[4];
    const unsigned short* c_bpeb = canon + ca.off[5];
    const unsigned short* c_Wq   = canon + ca.off[6];
    const unsigned short* c_bq   = canon + ca.off[7];
    const unsigned short* c_Wk   = canon + ca.off[8];
    const unsigned short* c_bk   = canon + ca.off[9];
    const unsigned short* c_Wv   = canon + ca.off[10];
    const unsigned short* c_bv   = canon + ca.off[11];
    const unsigned short* c_Wo   = canon + ca.off[12];
    const unsigned short* c_bo   = canon + ca.off[13];
    const unsigned short* c_W1   = canon + ca.off[14];
    const unsigned short* c_b1   = canon + ca.off[15];
    const unsigned short* c_W2   = canon + ca.off[16];
    const unsigned short* c_b2   = canon + ca.off[17];
    const unsigned short* c_pw1  = canon + ca.off[18];
    const unsigned short* c_pb1  = canon + ca.off[19];
    const unsigned short* c_pw2  = canon + ca.off[20];
    const unsigned short* c_pb2  = canon + ca.off[21];

    detect_kernel<<<1, 256, 0, stream>>>((const unsigned short*)d_in[2], flag);
    convert_kernel<<<(total + 255) / 256, 256, 0, stream>>>(ca, flag, canon, total);

    prep_trans_kernel<<<(155648 + 255) / 256, 256, 0, stream>>>(
        c_Wq, c_W1, c_W2, c_pw1, wqT, w1T, w2T, pw1T);

    encode_kernel<<<M / 8, 256, 0, stream>>>(c_bpts, c_bpew, c_bpeb, b_enc);
    zero_kernel<<<50, 256, 0, stream>>>(kvs, 12288 + 384);
    khvh_kernel<<<(12 * M * 32) / 256, 256, 0, stream>>>(b_enc, c_Wk, c_bk, c_Wv, c_bv, khb, vhb);
    kvred_kernel<<<96, 1024, 0, stream>>>(khb, vhb, kvs, kss);
    prep_wa_kernel<<<(55296 + 255) / 256, 256, 0, stream>>>(kvs, kss, c_Wo, waT, ksT);

    mega_kernel<<<N / 64, 256, 0, stream>>>(
        c_qpts, c_pew, c_peb, wqT, waT, ksT, w1T, w2T,
        c_bq, c_bo, c_b1, c_b2, pw1T, c_pb1, c_pw2, c_pb2, d_out, flag);
}

// Round 5
// 817.213 us; speedup vs baseline: 3.4263x; 1.0739x over previous
//
#include <hip/hip_runtime.h>
#include <hip/hip_bf16.h>

// ---------- helpers ----------
__device__ __forceinline__ float b2f(unsigned short u) {
    return __uint_as_float(((unsigned)u) << 16);
}
__device__ __forceinline__ unsigned short f2b(float f) {
    __hip_bfloat16 h = __float2bfloat16(f);
    return *reinterpret_cast<unsigned short*>(&h);
}
// cheap round-to-nearest-even bf16 (no NaN inputs in this pipeline)
__device__ __forceinline__ unsigned short f2b_rne(float f) {
    unsigned u = __float_as_uint(f);
    return (unsigned short)((u + 0x7fffu + ((u >> 16) & 1u)) >> 16);
}
__device__ __forceinline__ float sigm(float v) {
    return 1.f / (1.f + __expf(-v));
}
// tanh-approx GELU (max abs dev from exact ~1e-3; post-W2 contribution <1e-3)
__device__ __forceinline__ float gelu_t(float x) {
    float y = 0.7978845608f * (x + 0.044715f * x * x * x);
    float e = __expf(2.f * y);
    float th = 1.f - 2.f / (e + 1.f);
    return 0.5f * x * (1.f + th);
}

typedef __attribute__((ext_vector_type(8))) short s8v;   // 8 bf16 (4 VGPRs)
typedef __attribute__((ext_vector_type(4))) float f4v;   // 4 fp32 acc

#define MFMA_BF16 __builtin_amdgcn_mfma_f32_16x16x32_bf16

// ---------- 15-feature map (per input coordinate) ----------
__device__ __forceinline__ void make_feats(const unsigned short* __restrict__ qpts,
                                           int r, float* __restrict__ f) {
    unsigned pq = *(const unsigned*)(qpts + (size_t)r * 2);
    float x0 = b2f((unsigned short)(pq & 0xffff));
    float x1 = b2f((unsigned short)(pq >> 16));
    const float PI = 3.14159265358979323846f;
    float a0 = x0 - 1.5f, a1 = x1 - 1.5f, c0 = x0 - 4.5f, c1 = x1 - 4.5f;
    f[0] = x0;        f[1] = x1;
    f[2] = x0 * x0;   f[3] = x1 * x1;
    f[4] = a0 * a0;   f[5] = a1 * a1;
    f[6] = c0 * c0;   f[7] = c1 * c1;
    f[8] = sigm(x0);  f[9] = sigm(x1);
    f[10] = sigm(a0); f[11] = sigm(a1);
    f[12] = sigm(c0); f[13] = sigm(c1);
    f[14] = a0;       f[15] = a1;
    f[16] = c0;       f[17] = c1;
    f[18] = __sinf(PI * x0);          f[19] = __sinf(PI * x1);
    f[20] = __cosf(PI * x0);          f[21] = __cosf(PI * x1);
    f[22] = __sinf(PI * 0.25f * x0);  f[23] = __sinf(PI * 0.25f * x1);
    f[24] = __cosf(PI * 0.25f * x0);  f[25] = __cosf(PI * 0.25f * x1);
    f[26] = __sinf(PI * 0.5f * x0);   f[27] = __sinf(PI * 0.5f * x1);
    f[28] = __cosf(PI * 0.5f * x0);   f[29] = __cosf(PI * 0.5f * x1);
}

// ---------- canonicalize all inputs to bf16 (embedded dtype detection) ----------
struct ConvArgs {
    const void* p[22];
    int off[23];
};

__global__ __launch_bounds__(256) void convert_kernel(
    ConvArgs a, const unsigned short* __restrict__ pe_w_raw,
    int* __restrict__ flag, unsigned short* __restrict__ canon, int total)
{
    __shared__ int cnt;
    if (threadIdx.x == 0) cnt = 0;
    __syncthreads();
    // bf16 weights are N(0,0.05^2): |v|<1 always. f32-reinterpreted even
    // ushorts are mantissa bits -> random exponents -> ~half have |v|>=1.
    float v = b2f(pe_w_raw[threadIdx.x * 2]);
    if (!(fabsf(v) < 1.0f)) atomicAdd(&cnt, 1);
    __syncthreads();
    int isf32 = (cnt >= 16) ? 1 : 0;
    if (blockIdx.x == 0 && threadIdx.x == 0) *flag = isf32;

    int g = blockIdx.x * 256 + threadIdx.x;
    if (g >= total) return;
    int s = 0;
    #pragma unroll
    for (int i = 1; i < 23; i++) s += (g >= a.off[i]) ? 1 : 0;
    int local = g - a.off[s];
    unsigned short r;
    if (isf32) r = f2b(((const float*)a.p[s])[local]);
    else       r = ((const unsigned short*)a.p[s])[local];
    canon[g] = r;
}

// ---------- boundary positional encoding (M rows, fp32 out) ----------
__global__ __launch_bounds__(256) void encode_kernel(
    const unsigned short* __restrict__ pts,
    const unsigned short* __restrict__ w,
    const unsigned short* __restrict__ b,
    float* __restrict__ out)
{
    __shared__ __align__(16) float wsm[30 * 128];
    __shared__ float bs[128];
    int t = threadIdx.x;
    for (int i = t; i < 30 * 128; i += 256) wsm[i] = b2f(w[i]);
    if (t < 128) bs[t] = b2f(b[t]);
    __syncthreads();

    int r = blockIdx.x * 8 + (t >> 5);
    int j = t & 31;
    float f[30];
    make_feats(pts, r, f);
    float s0 = bs[j * 4 + 0], s1 = bs[j * 4 + 1], s2 = bs[j * 4 + 2], s3 = bs[j * 4 + 3];
    #pragma unroll
    for (int ff = 0; ff < 30; ff++) {
        float4 wv = *(const float4*)&wsm[ff * 128 + j * 4];
        float fv = f[ff];
        s0 += fv * wv.x; s1 += fv * wv.y; s2 += fv * wv.z; s3 += fv * wv.w;
    }
    *(float4*)&out[(size_t)r * 128 + j * 4] =
        make_float4(__sinf(s0), __sinf(s1), __sinf(s2), __sinf(s3));
}

// ---------- boundary k/v heads (+ zeroing of kv/ks accumulators) ----------
__global__ __launch_bounds__(256) void khvh_kernel(
    const float* __restrict__ benc,
    const unsigned short* __restrict__ Wk, const unsigned short* __restrict__ bk,
    const unsigned short* __restrict__ Wv, const unsigned short* __restrict__ bv,
    float* __restrict__ kh, float* __restrict__ vh, float* __restrict__ kvz)
{
    int g = blockIdx.x * 256 + threadIdx.x;
    if (g < 12672) kvz[g] = 0.f;   // kvs(12288) + kss(384), contiguous
    int lh = g >> 17;
    int rem = g & 131071;
    int m = rem >> 5;
    int dd = rem & 31;
    const unsigned short* wk = Wk + lh * 4096 + dd;
    const unsigned short* wv = Wv + lh * 4096 + dd;
    const float* br = benc + (size_t)m * 128;
    float ka = 0.f, va = 0.f;
    #pragma unroll 8
    for (int c = 0; c < 128; c++) {
        float bb = br[c];
        ka += bb * b2f(wk[c * 32]);
        va += bb * b2f(wv[c * 32]);
    }
    ka += b2f(bk[lh * 32 + dd]); ka = ka * ka;
    va += b2f(bv[lh * 32 + dd]);
    kh[g] = ka; vh[g] = va;
}

// ---------- reduce over boundary points: kvsum[lh][d][e], ksum[lh][d] ----------
__global__ __launch_bounds__(1024) void kvred_kernel(
    const float* __restrict__ kh, const float* __restrict__ vh,
    float* __restrict__ kvsum, float* __restrict__ ksum)
{
    __shared__ float khs[1024];
    __shared__ float vhs[1024];
    int t = threadIdx.x;
    int lh = blockIdx.x >> 3;
    int part = blockIdx.x & 7;
    int dd = t >> 5, ee = t & 31;
    float kva = 0.f, ksa = 0.f;
    for (int ch = 0; ch < 16; ch++) {
        int base = lh * 131072 + (part * 16 + ch) * 1024;
        khs[t] = kh[base + t];
        vhs[t] = vh[base + t];
        __syncthreads();
        #pragma unroll
        for (int i = 0; i < 32; i++) {
            float kk = khs[i * 32 + dd];
            kva += kk * vhs[i * 32 + ee];
            ksa += kk;
        }
        __syncthreads();
    }
    atomicAdd(&kvsum[lh * 1024 + dd * 32 + ee], kva);
    if (ee == 0) atomicAdd(&ksum[lh * 32 + dd], ksa);
}

// ---------- prep: transposes + Wa fold + Ks matrix, one kernel ----------
__global__ __launch_bounds__(256) void prep_kernel(
    const unsigned short* __restrict__ Wq, const unsigned short* __restrict__ W1,
    const unsigned short* __restrict__ W2, const unsigned short* __restrict__ pw1,
    const float* __restrict__ kvs, const float* __restrict__ kss,
    const unsigned short* __restrict__ Wo,
    unsigned short* __restrict__ wqT, unsigned short* __restrict__ w1T,
    unsigned short* __restrict__ w2T, unsigned short* __restrict__ pw1T,
    unsigned short* __restrict__ waT, unsigned short* __restrict__ ksT)
{
    int g = blockIdx.x * 256 + threadIdx.x;
    if (g < 49152) {
        int l = g >> 14, r = g & 16383, n = r >> 7, k = r & 127;
        wqT[g] = Wq[((l * 4 + (n >> 5)) * 128 + k) * 32 + (n & 31)];  // head-interleaved cols
    } else if (g < 98304) {
        int q = g - 49152; int l = q >> 14, r = q & 16383, n = r >> 7, k = r & 127;
        w1T[q] = W1[(l * 128 + k) * 128 + n];
    } else if (g < 147456) {
        int q = g - 98304; int l = q >> 14, r = q & 16383, n = r >> 7, k = r & 127;
        w2T[q] = W2[(l * 128 + k) * 128 + n];
    } else if (g < 155648) {
        int q = g - 147456; int n = q >> 7, k = q & 127;
        pw1T[q] = pw1[k * 64 + n];
    } else if (g < 204800) {
        int q = g - 155648; int l = q >> 14, r = q & 16383, n = r >> 7, k = r & 127;
        int hk = k >> 5, dk = k & 31;
        const float* kvp = kvs + (l * 4 + hk) * 1024 + dk * 32;
        const unsigned short* wop = Wo + (size_t)(l * 128 + hk * 32) * 128 + n;
        float s = 0.f;
        #pragma unroll 8
        for (int j = 0; j < 32; j++) s += kvp[j] * b2f(wop[j * 128]);
        waT[q] = f2b(s);
    } else if (g < 210944) {
        int q = g - 204800; int l = q >> 11, r = q & 2047, n = r >> 7, k = r & 127;
        unsigned short v = 0;
        if (n < 4 && (k >> 5) == n) v = f2b(kss[(l * 4 + n) * 32 + (k & 31)]);
        ksT[q] = v;
    }
}

// ---------- the fused mega kernel: encode + 3 layers + projector ----------
// 128 rows/block, 4 waves; wave w owns rows [w*32, w*32+32) = 2 MFMA row-tiles.
// Weights read as B-fragments DIRECTLY FROM GLOBAL (L2-hot) -> no weight
// staging, no barriers in the layer loop (activations are wave-private;
// same-wave LDS ops execute in order). MFMA 16x16x32 bf16:
// A[m=lane&15][k=quad*8+j]; B-frag reads row n=lane&15 of [n][k] weights;
// C/D: row=quad*4+reg, col=lane&15 (m89-verified).
#define LDA 136   // LDS row stride in ushorts (272B = 17*16B)

__global__ __launch_bounds__(256, 2) void mega_kernel(
    const unsigned short* __restrict__ qpts,
    const unsigned short* __restrict__ pe_w,
    const unsigned short* __restrict__ pe_b,
    const unsigned short* __restrict__ wqT,
    const unsigned short* __restrict__ waT,
    const unsigned short* __restrict__ ksT,
    const unsigned short* __restrict__ w1T,
    const unsigned short* __restrict__ w2T,
    const unsigned short* __restrict__ bq,
    const unsigned short* __restrict__ bo,
    const unsigned short* __restrict__ b1,
    const unsigned short* __restrict__ b2,
    const unsigned short* __restrict__ pw1T,
    const unsigned short* __restrict__ pb1,
    const unsigned short* __restrict__ pw2,
    const unsigned short* __restrict__ pb2,
    void* __restrict__ outv, const int* __restrict__ flag)
{
    __shared__ __align__(16) unsigned short sA[128 * LDA];   // 34816 B activations
    __shared__ __align__(16) float pws[30 * 128];            // 15360 B
    __shared__ __align__(16) unsigned short sKsAll[3 * 16 * LDA]; // 13056 B
    __shared__ float biasAll[12 * 128];                      // 6144 B [l][{q,o,1,2}][c]
    __shared__ float pebs[128];
    __shared__ float pb1s[64];
    __shared__ float w2s[192];
    __shared__ float pb2s[3];
    __shared__ float dens[128 * 4];                          // 2048 B

    int t = threadIdx.x;
    int wvi = t >> 6, ln = t & 63, qd = ln >> 4, l16 = ln & 15;
    int row0 = blockIdx.x * 128;
    int rA0 = wvi * 32 + l16;        // A-frag row, tile 0
    int r0c = wvi * 32 + qd * 4;     // C base row, tile 0 (tile 1: +16)

    // ===== one-time staging =====
    for (int i = t; i < 3840; i += 256) pws[i] = b2f(pe_w[i]);
    #pragma unroll
    for (int ll = 0; ll < 3; ll++)
        *(int4*)&sKsAll[(ll * 16 + (t >> 4)) * LDA + (t & 15) * 8] =
            ((const int4*)(ksT + ll * 2048))[t];
    for (int i = t; i < 1536; i += 256) {
        int l = i >> 9, rem = i & 511, which = rem >> 7, c = rem & 127;
        const unsigned short* bsrc = (which == 0) ? bq : (which == 1) ? bo
                                   : (which == 2) ? b1 : b2;
        biasAll[i] = b2f(bsrc[l * 128 + c]);
    }
    if (t < 128) pebs[t] = b2f(pe_b[t]);
    if (t < 64)  pb1s[t] = b2f(pb1[t]);
    if (t < 192) w2s[t] = b2f(pw2[t]);
    if (t < 3)   pb2s[t] = b2f(pb2[t]);
    __syncthreads();     // barrier #1 (the only one before the tail)

    // ===== encode: h = sin(feats @ pe_w + pe_b), vectorized cols =====
    // lane covers rows {wvi*32 + qd*8 + rp*2 + 0/1}, cols [l16*8, l16*8+8)
    {
        const float4* pws4 = (const float4*)pws;   // [30][32]
        const float4* peb4 = (const float4*)pebs;  // [32]
        float4 pbA = peb4[l16 * 2], pbB = peb4[l16 * 2 + 1];
        for (int rp = 0; rp < 4; rp++) {
            int rl = wvi * 32 + qd * 8 + rp * 2;
            float f0[30], f1[30];
            make_feats(qpts, row0 + rl, f0);
            make_feats(qpts, row0 + rl + 1, f1);
            float a0[8] = {pbA.x, pbA.y, pbA.z, pbA.w, pbB.x, pbB.y, pbB.z, pbB.w};
            float a1[8] = {pbA.x, pbA.y, pbA.z, pbA.w, pbB.x, pbB.y, pbB.z, pbB.w};
            #pragma unroll
            for (int ff = 0; ff < 30; ff++) {
                float4 wa = pws4[ff * 32 + l16 * 2];
                float4 wb = pws4[ff * 32 + l16 * 2 + 1];
                float v0 = f0[ff], v1 = f1[ff];
                a0[0] += v0 * wa.x; a0[1] += v0 * wa.y; a0[2] += v0 * wa.z; a0[3] += v0 * wa.w;
                a0[4] += v0 * wb.x; a0[5] += v0 * wb.y; a0[6] += v0 * wb.z; a0[7] += v0 * wb.w;
                a1[0] += v1 * wa.x; a1[1] += v1 * wa.y; a1[2] += v1 * wa.z; a1[3] += v1 * wa.w;
                a1[4] += v1 * wb.x; a1[5] += v1 * wb.y; a1[6] += v1 * wb.z; a1[7] += v1 * wb.w;
            }
            s8v h0, h1;
            #pragma unroll
            for (int j = 0; j < 8; j++) {
                h0[j] = (short)f2b_rne(__sinf(a0[j]));
                h1[j] = (short)f2b_rne(__sinf(a1[j]));
            }
            *(s8v*)&sA[rl * LDA + l16 * 8] = h0;
            *(s8v*)&sA[(rl + 1) * LDA + l16 * 8] = h1;
        }
    }

    // residual h in C-layout regs (bf16-rounded base; fp32 thereafter)
    float hres[2][4][8];
    #pragma unroll
    for (int tile = 0; tile < 2; tile++)
        #pragma unroll
        for (int i = 0; i < 4; i++)
            #pragma unroll
            for (int tc = 0; tc < 8; tc++)
                hres[tile][i][tc] =
                    b2f(sA[(r0c + tile * 16 + i) * LDA + tc * 16 + l16]);

    // A-frag loader from sA (wave-private rows)
    auto load_af = [&](s8v a[2][4]) {
        #pragma unroll
        for (int tile = 0; tile < 2; tile++)
            #pragma unroll
            for (int ks = 0; ks < 4; ks++)
                a[tile][ks] = *(const s8v*)&sA[(rA0 + tile * 16) * LDA + ks * 32 + qd * 8];
    };
    // mm over 8 col-tiles, B-frags from global with prefetch-1
    auto run_mm = [&](const s8v a[2][4], const unsigned short* W, auto&& epi) {
        const unsigned short* base = W + l16 * 128 + qd * 8;
        s8v cur[4], nxt[4];
        #pragma unroll
        for (int ks = 0; ks < 4; ks++) cur[ks] = *(const s8v*)(base + ks * 32);
        #pragma unroll
        for (int tc = 0; tc < 8; tc++) {
            if (tc < 7) {
                const unsigned short* bp = base + (tc + 1) * 2048;
                #pragma unroll
                for (int ks = 0; ks < 4; ks++) nxt[ks] = *(const s8v*)(bp + ks * 32);
            }
            f4v x0 = {0.f, 0.f, 0.f, 0.f}, x1 = {0.f, 0.f, 0.f, 0.f};
            #pragma unroll
            for (int ks = 0; ks < 4; ks++) {
                x0 = MFMA_BF16(a[0][ks], cur[ks], x0, 0, 0, 0);
                x1 = MFMA_BF16(a[1][ks], cur[ks], x1, 0, 0, 0);
            }
            epi(tc, x0, x1);
            if (tc < 7) {
                #pragma unroll
                for (int ks = 0; ks < 4; ks++) cur[ks] = nxt[ks];
            }
        }
    };

    // ===== 3 transformer layers (no barriers) =====
    for (int l = 0; l < 3; l++) {
        const float* bql = &biasAll[(l * 4 + 0) * 128];
        const float* bol = &biasAll[(l * 4 + 1) * 128];
        const float* b1l = &biasAll[(l * 4 + 2) * 128];
        const float* b2l = &biasAll[(l * 4 + 3) * 128];

        s8v af[2][4];
        load_af(af);   // h
        // mm1: qh = (h @ Wq + bq)^2 -> sA
        run_mm(af, wqT + l * 16384, [&](int tc, f4v x0, f4v x1) {
            int c = tc * 16 + l16;
            float bb = bql[c];
            #pragma unroll
            for (int i = 0; i < 4; i++) {
                float v0 = x0[i] + bb;
                sA[(r0c + i) * LDA + c] = f2b_rne(v0 * v0);
                float v1 = x1[i] + bb;
                sA[(r0c + 16 + i) * LDA + c] = f2b_rne(v1 * v1);
            }
        });

        // den: dens[r][h] = qh_r . ksum_h   (B from LDS sKs)
        s8v qf[2][4];
        load_af(qf);   // qh
        #pragma unroll
        for (int tile = 0; tile < 2; tile++) {
            f4v d = {0.f, 0.f, 0.f, 0.f};
            #pragma unroll
            for (int ks = 0; ks < 4; ks++) {
                s8v bf = *(const s8v*)&sKsAll[(l * 16 + l16) * LDA + ks * 32 + qd * 8];
                d = MFMA_BF16(qf[tile][ks], bf, d, 0, 0, 0);
            }
            if (l16 < 4) {
                #pragma unroll
                for (int i = 0; i < 4; i++)
                    dens[(r0c + tile * 16 + i) * 4 + l16] = d[i];
            }
        }
        // scale qh fragments by z = 1/(den+1e-6); head of k-step ks == ks
        #pragma unroll
        for (int tile = 0; tile < 2; tile++) {
            int mr = rA0 + tile * 16;
            #pragma unroll
            for (int ks = 0; ks < 4; ks++) {
                float z = 1.f / (dens[mr * 4 + ks] + 1e-6f);
                #pragma unroll
                for (int j = 0; j < 8; j++) {
                    float q = b2f((unsigned short)qf[tile][ks][j]);
                    qf[tile][ks][j] = (short)f2b_rne(q * z);
                }
            }
        }

        // mm2: x = h + (z*qh) @ Wa + bo -> hres(fp32), sA(bf16)
        run_mm(qf, waT + l * 16384, [&](int tc, f4v x0, f4v x1) {
            int c = tc * 16 + l16;
            float bb = bol[c];
            #pragma unroll
            for (int i = 0; i < 4; i++) {
                float v0 = hres[0][i][tc] + x0[i] + bb;
                hres[0][i][tc] = v0;
                sA[(r0c + i) * LDA + c] = f2b_rne(v0);
                float v1 = hres[1][i][tc] + x1[i] + bb;
                hres[1][i][tc] = v1;
                sA[(r0c + 16 + i) * LDA + c] = f2b_rne(v1);
            }
        });

        // mm3: t = gelu(x @ W1 + b1) -> sA
        load_af(af);   // x
        run_mm(af, w1T + l * 16384, [&](int tc, f4v x0, f4v x1) {
            int c = tc * 16 + l16;
            float bb = b1l[c];
            #pragma unroll
            for (int i = 0; i < 4; i++) {
                sA[(r0c + i) * LDA + c] = f2b_rne(gelu_t(x0[i] + bb));
                sA[(r0c + 16 + i) * LDA + c] = f2b_rne(gelu_t(x1[i] + bb));
            }
        });

        // mm4: h_new = x + t @ W2 + b2 -> hres, sA
        load_af(af);   // t
        run_mm(af, w2T + l * 16384, [&](int tc, f4v x0, f4v x1) {
            int c = tc * 16 + l16;
            float bb = b2l[c];
            #pragma unroll
            for (int i = 0; i < 4; i++) {
                float v0 = hres[0][i][tc] + x0[i] + bb;
                hres[0][i][tc] = v0;
                sA[(r0c + i) * LDA + c] = f2b_rne(v0);
                float v1 = hres[1][i][tc] + x1[i] + bb;
                hres[1][i][tc] = v1;
                sA[(r0c + 16 + i) * LDA + c] = f2b_rne(v1);
            }
        });
    }

    // ===== final projector: out = gelu(h @ pw1 + pb1) @ pw2 + pb2 =====
    {
        s8v af[2][4];
        load_af(af);
        float* sAf = (float*)sA;   // [128][68] fp32 view (row = 272B = LDA)
        const unsigned short* base = pw1T + l16 * 128 + qd * 8;
        #pragma unroll
        for (int tc = 0; tc < 4; tc++) {
            s8v cur[4];
            #pragma unroll
            for (int ks = 0; ks < 4; ks++)
                cur[ks] = *(const s8v*)(base + tc * 2048 + ks * 32);
            f4v x0 = {0.f, 0.f, 0.f, 0.f}, x1 = {0.f, 0.f, 0.f, 0.f};
            #pragma unroll
            for (int ks = 0; ks < 4; ks++) {
                x0 = MFMA_BF16(af[0][ks], cur[ks], x0, 0, 0, 0);
                x1 = MFMA_BF16(af[1][ks], cur[ks], x1, 0, 0, 0);
            }
            int c = tc * 16 + l16;
            float bb = pb1s[c];
            #pragma unroll
            for (int i = 0; i < 4; i++) {
                sAf[(r0c + i) * 68 + c] = gelu_t(x0[i] + bb);
                sAf[(r0c + 16 + i) * 68 + c] = gelu_t(x1[i] + bb);
            }
        }
    }
    __syncthreads();   // barrier #2: cross-wave read below

    {
        const float* sAf = (const float*)sA;
        for (int idx = t; idx < 384; idx += 256) {
            int r = idx / 3, c = idx - r * 3;
            float s = pb2s[c];
            #pragma unroll 8
            for (int j = 0; j < 64; j++) s += sAf[r * 68 + j] * w2s[j * 3 + c];
            size_t o = (size_t)(row0 + r) * 3 + c;
            if (*flag) ((float*)outv)[o] = s;
            else       ((unsigned short*)outv)[o] = f2b(s);
        }
    }
}

// ---------- launch ----------
extern "C" void kernel_launch(void* const* d_in, const int* in_sizes, int n_in,
                              void* d_out, int out_size, void* d_ws, size_t ws_size,
                              hipStream_t stream) {
    const int N = in_sizes[0] / 2;   // 262144
    const int M = in_sizes[1] / 2;   // 4096

    ConvArgs ca;
    int total = 0;
    for (int i = 0; i < 22; i++) { ca.p[i] = d_in[i]; ca.off[i] = total; total += in_sizes[i]; }
    ca.off[22] = total;

    float* ws = (float*)d_ws;
    int* flag = (int*)ws;
    unsigned short* canon = (unsigned short*)(ws + 16);
    size_t canonF = ((size_t)(total + 1) / 2 + 15) & ~(size_t)15;
    float* b_enc = ws + 16 + canonF;                       // M*128
    float* khb   = b_enc + (size_t)M * 128;                // 12*M*32
    float* vhb   = khb + (size_t)12 * M * 32;              // 12*M*32
    float* kvs   = vhb + (size_t)12 * M * 32;              // 12288
    float* kss   = kvs + 12288;                            // 384
    unsigned short* wqT  = (unsigned short*)(kss + 384);   // 3*16384
    unsigned short* waT  = wqT + 49152;
    unsigned short* w1T  = waT + 49152;
    unsigned short* w2T  = w1T + 49152;
    unsigned short* ksT  = w2T + 49152;                    // 3*2048
    unsigned short* pw1T = ksT + 6144;                     // 8192

    const unsigned short* c_qpts = canon + ca.off[0];
    const unsigned short* c_bpts = canon + ca.off[1];
    const unsigned short* c_pew  = canon + ca.off[2];
    const unsigned short* c_peb  = canon + ca.off[3];
    const unsigned short* c_bpew = canon + ca.off[4];
    const unsigned short* c_bpeb = canon + ca.off[5];
    const unsigned short* c_Wq   = canon + ca.off[6];
    const unsigned short* c_bq   = canon + ca.off[7];
    const unsigned short* c_Wk   = canon + ca.off[8];
    const unsigned short* c_bk   = canon + ca.off[9];
    const unsigned short* c_Wv   = canon + ca.off[10];
    const unsigned short* c_bv   = canon + ca.off[11];
    const unsigned short* c_Wo   = canon + ca.off[12];
    const unsigned short* c_bo   = canon + ca.off[13];
    const unsigned short* c_W1   = canon + ca.off[14];
    const unsigned short* c_b1   = canon + ca.off[15];
    const unsigned short* c_W2   = canon + ca.off[16];
    const unsigned short* c_b2   = canon + ca.off[17];
    const unsigned short* c_pw1  = canon + ca.off[18];
    const unsigned short* c_pb1  = canon + ca.off[19];
    const unsigned short* c_pw2  = canon + ca.off[20];
    const unsigned short* c_pb2  = canon + ca.off[21];

    convert_kernel<<<(total + 255) / 256, 256, 0, stream>>>(
        ca, (const unsigned short*)d_in[2], flag, canon, total);

    encode_kernel<<<M / 8, 256, 0, stream>>>(c_bpts, c_bpew, c_bpeb, b_enc);
    khvh_kernel<<<(12 * M * 32) / 256, 256, 0, stream>>>(
        b_enc, c_Wk, c_bk, c_Wv, c_bv, khb, vhb, kvs);
    kvred_kernel<<<96, 1024, 0, stream>>>(khb, vhb, kvs, kss);
    prep_kernel<<<(210944 + 255) / 256, 256, 0, stream>>>(
        c_Wq, c_W1, c_W2, c_pw1, kvs, kss, c_Wo,
        wqT, w1T, w2T, pw1T, waT, ksT);

    mega_kernel<<<N / 128, 256, 0, stream>>>(
        c_qpts, c_pew, c_peb, wqT, waT, ksT, w1T, w2T,
        c_bq, c_bo, c_b1, c_b2, pw1T, c_pb1, c_pw2, c_pb2, d_out, flag);
}